// Round 10
// baseline (3225.647 us; speedup 1.0000x reference)
//
#include <hip/hip_runtime.h>
#include <hip/hip_bf16.h>

// ViT forward, MI355X gfx950. Round 10: 256^2 8-wave phase-pipelined GEMM (T3+T4+T5,
// conservative vmcnt(2)-per-phase ledger, never 0 in-loop) for QKV and FC1.
// All other kernels identical to R9 (2761us baseline).

typedef __bf16 bf16;
typedef __bf16 bf16x8 __attribute__((ext_vector_type(8)));
typedef __bf16 bf16x4 __attribute__((ext_vector_type(4)));
typedef float  f32x4  __attribute__((ext_vector_type(4)));

typedef __attribute__((address_space(1))) const unsigned int gu32;
typedef __attribute__((address_space(3))) unsigned int lu32;

static __device__ __forceinline__ f32x4 mfma_bf16(bf16x8 a, bf16x8 b, f32x4 c) {
  return __builtin_amdgcn_mfma_f32_16x16x32_bf16(a, b, c, 0, 0, 0);
}
static __device__ __forceinline__ void gll16(const bf16* g, bf16* l) {
  __builtin_amdgcn_global_load_lds((gu32*)g, (lu32*)l, 16, 0, 0);
}

// ---------------- small setup kernels ----------------

__global__ __launch_bounds__(256) void f2b_k(const float* __restrict__ a, bf16* __restrict__ o, int n) {
  int i = blockIdx.x * 256 + threadIdx.x;
  if (i < n) o[i] = (bf16)a[i];
}

__global__ __launch_bounds__(256) void posenc_k(float* __restrict__ pos) {
  int l = blockIdx.x;
  for (int d = threadIdx.x; d < 768; d += 256) {
    int ieff = d & ~1;
    float ang = (float)l * expf(-(float)ieff * (9.210340371976184f / 768.0f)); // 10000^{-i/768}
    pos[l * 768 + d] = (d & 1) ? cosf(ang) : sinf(ang);
  }
}

// patches[t, c*256+i*16+j] = x[b, c, ph*16+i, pw*16+j],  t = b*196 + ph*14 + pw
__global__ __launch_bounds__(256) void patchify_k(const float* __restrict__ x, bf16* __restrict__ p) {
  int idx = blockIdx.x * 256 + threadIdx.x;     // 6272*768 exact
  int t = idx / 768, col = idx - t * 768;
  int b = t / 196, pp = t - b * 196;
  int ph = pp / 14, pw = pp - ph * 14;
  int c = col >> 8, r = col & 255, i = r >> 4, j = r & 15;
  p[idx] = (bf16)x[((b * 3 + c) * 224 + ph * 16 + i) * 224 + pw * 16 + j];
}

// CLS row: h[b*197+0, :] = cls + pos[0]
__global__ __launch_bounds__(256) void cls_k(float* __restrict__ h, const float* __restrict__ pos,
                                             const float* __restrict__ cls) {
  int b = blockIdx.x;
  for (int d = threadIdx.x; d < 768; d += 256)
    h[((size_t)b * 197) * 768 + d] = cls[d] + pos[d];
}

// LayerNorm over 768, one wave per row, 4 rows/block, bf16 out.
// PAD=1: output row index remapped t=b*197+l -> b*200+l (QKV-GEMM B operand layout).
template<int PAD>
__global__ __launch_bounds__(256) void ln4_k(const float* __restrict__ x, const float* __restrict__ g,
                                             const float* __restrict__ bb, bf16* __restrict__ y,
                                             int nrows, int instride) {
  const int wave = threadIdx.x >> 6, lane = threadIdx.x & 63;
  const int row = blockIdx.x * 4 + wave;
  if (row >= nrows) return;
  const float4* x4 = (const float4*)(x + (size_t)row * instride);
  float4 v0 = x4[lane], v1 = x4[lane + 64], v2 = x4[lane + 128];
  float s  = v0.x + v0.y + v0.z + v0.w + v1.x + v1.y + v1.z + v1.w + v2.x + v2.y + v2.z + v2.w;
  float s2 = v0.x*v0.x + v0.y*v0.y + v0.z*v0.z + v0.w*v0.w
           + v1.x*v1.x + v1.y*v1.y + v1.z*v1.z + v1.w*v1.w
           + v2.x*v2.x + v2.y*v2.y + v2.z*v2.z + v2.w*v2.w;
  #pragma unroll
  for (int o = 1; o < 64; o <<= 1) { s += __shfl_xor(s, o); s2 += __shfl_xor(s2, o); }
  float m = s * (1.0f / 768.0f);
  float inv = rsqrtf(s2 * (1.0f / 768.0f) - m * m + 1e-5f);
  int orow = row;
  if (PAD) { int bq = row / 197; orow = row + bq * 3; }
  bf16* yr = y + (size_t)orow * 768;
  const float4* g4 = (const float4*)g;
  const float4* b4 = (const float4*)bb;
  #pragma unroll
  for (int i = 0; i < 3; ++i) {
    int idx = lane + i * 64;
    float4 vv = (i == 0) ? v0 : (i == 1) ? v1 : v2;
    float4 gv = g4[idx], bv = b4[idx];
    bf16x4 o;
    o[0] = (bf16)((vv.x - m) * inv * gv.x + bv.x);
    o[1] = (bf16)((vv.y - m) * inv * gv.y + bv.y);
    o[2] = (bf16)((vv.z - m) * inv * gv.z + bv.z);
    o[3] = (bf16)((vv.w - m) * inv * gv.w + bv.w);
    *(bf16x4*)(yr + idx * 4) = o;
  }
}

// ---------------- NT GEMM, R3 structure (single-buffer, 2D grid) ----------------
// EPI: 0=PROJ (h row remap + pos add, fp32)  2=ACCUM (outF[t*768+col]+=)
//      4=TANH (bf16, stride 768)   5=GUARDED fp32 store (stride ldc, col<N)
template<int BN, int EPI>
__global__ __launch_bounds__(256) void gemm2(
    const bf16* __restrict__ A, const bf16* __restrict__ B,
    int M, int N, int K, int ldc, const float* __restrict__ bias,
    const float* __restrict__ posw,
    float* __restrict__ outF, bf16* __restrict__ outB)
{
  constexpr int WN = (BN == 128) ? 64 : 32;
  constexpr int NI = WN / 16;
  constexpr int NB = BN / 32;
  __shared__ alignas(16) bf16 As[128 * 64];
  __shared__ alignas(16) bf16 Bs[BN * 64];
  const int tid = threadIdx.x;
  const int lane = tid & 63, wave = tid >> 6;
  const int wr = wave >> 1, wc = wave & 1;
  const int lrow = lane & 15, lgrp = lane >> 4;
  const int row0 = blockIdx.x * 128, col0 = blockIdx.y * BN;

  f32x4 acc[4][NI] = {};
  const bf16* Agb = A + (size_t)row0 * K;
  const bf16* Bgb = B + (size_t)col0 * K;
  const int srow = lane >> 3, schunk = lane & 7;
  const int nk = K >> 6;

  for (int kt = 0; kt < nk; ++kt) {
    const bf16* Ag = Agb + kt * 64;
    const bf16* Bg = Bgb + kt * 64;
    #pragma unroll
    for (int i = 0; i < 4; ++i) {
      int rr = (wave * 4 + i) * 8 + srow;
      int g = schunk ^ (rr & 7);
      gll16(Ag + (size_t)rr * K + g * 8, As + (wave * 4 + i) * 512);
    }
    #pragma unroll
    for (int i = 0; i < NB; ++i) {
      int rr = (wave * NB + i) * 8 + srow;
      int g = schunk ^ (rr & 7);
      gll16(Bg + (size_t)rr * K + g * 8, Bs + (wave * NB + i) * 512);
    }
    __syncthreads();
    #pragma unroll
    for (int kk = 0; kk < 2; ++kk) {
      bf16x8 af[4], bfr[NI];
      #pragma unroll
      for (int mi = 0; mi < 4; ++mi) {
        int r = wr * 64 + mi * 16 + lrow;
        af[mi] = *(const bf16x8*)(As + r * 64 + (((kk * 4 + lgrp) ^ (r & 7)) << 3));
      }
      #pragma unroll
      for (int ni = 0; ni < NI; ++ni) {
        int r = wc * WN + ni * 16 + lrow;
        bfr[ni] = *(const bf16x8*)(Bs + r * 64 + (((kk * 4 + lgrp) ^ (r & 7)) << 3));
      }
      #pragma unroll
      for (int mi = 0; mi < 4; ++mi)
        #pragma unroll
        for (int ni = 0; ni < NI; ++ni)
          acc[mi][ni] = mfma_bf16(af[mi], bfr[ni], acc[mi][ni]);
    }
    __syncthreads();
  }

  #pragma unroll
  for (int ni = 0; ni < NI; ++ni) {
    const int col = col0 + wc * WN + ni * 16 + lrow;
    float bs = (EPI == 5) ? ((col < N) ? bias[col] : 0.0f) : bias[col];
    #pragma unroll
    for (int mi = 0; mi < 4; ++mi) {
      const int rbase = row0 + wr * 64 + mi * 16 + (lgrp << 2);
      #pragma unroll
      for (int j = 0; j < 4; ++j) {
        const int t = rbase + j;
        if (t >= M) continue;
        float val = acc[mi][ni][j] + bs;
        if (EPI == 0) {
          int b = t / 196, p = t - b * 196;
          outF[((size_t)(b * 197 + 1 + p)) * 768 + col] = val + posw[(size_t)(1 + p) * 768 + col];
        } else if (EPI == 2) {
          outF[(size_t)t * 768 + col] += val;
        } else if (EPI == 4) {
          outB[(size_t)t * 768 + col] = (bf16)tanhf(val);
        } else {
          if (col < N) outF[(size_t)t * ldc + col] = val;
        }
      }
    }
  }
}

// ---------------- 256^2 8-wave phase-pipelined NT GEMM (QKV / FC1) ----------------
// C[M,N] = A[M,K]*B[N,K]^T. BM=BN=256, BK=64, 8 waves (2M x 4N), per-wave C = 128x64.
// LDS: 2 slots x {A[256][64], B[256][64]} = 128 KiB. Per K-tile: 4 phases (C m-quadrants);
// each phase stages ONE half-tile (2 gll16/wave) of the NEXT K-tile into the other slot,
// then s_waitcnt vmcnt(2): all halves except the just-issued one have landed -> the tile
// read after the barrier is complete (per-phase induction; never vmcnt(0) in-loop).
// EPI: 1=QKVT (bf16, bias by ROW, rows<768 *0.125, stride ldc)  3=FC1 gelu (stride 3072)
template<int EPI>
__global__ __launch_bounds__(512, 2) void gemm8(
    const bf16* __restrict__ A, const bf16* __restrict__ B,
    int M, int N, int K, int ldc, const float* __restrict__ bias,
    bf16* __restrict__ outB)
{
  __shared__ alignas(16) bf16 smem[2 * 2 * 256 * 64];   // [slot][mat][256*64]
  const int tid = threadIdx.x;
  const int lane = tid & 63, wave = tid >> 6;
  const int wm = wave >> 2, wn = wave & 3;              // 2M x 4N wave grid
  const int lrow = lane & 15, lgrp = lane >> 4;
  const int row0 = blockIdx.x * 256, col0 = blockIdx.y * 256;

  f32x4 acc[8][4] = {};
  const int srow = lane >> 3, schunk = lane & 7;
  const int nk = K >> 6;
  const bf16* Agb = A + (size_t)row0 * K;
  const bf16* Bgb = B + (size_t)col0 * K;

  // stage half h (0=rows 0-127, 1=rows 128-255) of matrix mat of K-tile kt into slot s
  auto stage_half = [&](int s, int mat, int h, int kt) {
    const bf16* G = (mat == 0 ? Agb : Bgb) + kt * 64;
    bf16* Lb = smem + (s * 2 + mat) * (256 * 64) + h * (128 * 64);
    #pragma unroll
    for (int shot = 0; shot < 2; ++shot) {
      int rloc = wave * 16 + shot * 8;                  // wave-uniform row base in half
      int rr = h * 128 + rloc + srow;                   // per-lane global row in tile
      int g = schunk ^ (rr & 7);
      gll16(G + (size_t)rr * K + g * 8, Lb + rloc * 64);
    }
  };

  // prologue: all 4 halves of tile 0 -> slot 0
  #pragma unroll
  for (int h = 0; h < 4; ++h) stage_half(0, h >> 1, h & 1, 0);
  asm volatile("s_waitcnt vmcnt(0)" ::: "memory");
  __builtin_amdgcn_s_barrier();

  bf16x8 bfrag[8];                                       // [n][kk]
  for (int g = 0; g < nk; ++g) {
    const int s = g & 1;
    const bf16* Asl = smem + (s * 2 + 0) * (256 * 64);
    const bf16* Bsl = smem + (s * 2 + 1) * (256 * 64);
    #pragma unroll
    for (int q = 0; q < 4; ++q) {
      if (g + 1 < nk) {
        stage_half(s ^ 1, q >> 1, q & 1, g + 1);         // one half of next tile
        asm volatile("s_waitcnt vmcnt(2)" ::: "memory"); // all but just-issued landed
      } else if (q == 0) {
        asm volatile("s_waitcnt vmcnt(0)" ::: "memory");
      }
      __builtin_amdgcn_sched_barrier(0);
      __builtin_amdgcn_s_barrier();
      if (q == 0) {                                      // B-frags once per K-tile
        #pragma unroll
        for (int n = 0; n < 4; ++n)
          #pragma unroll
          for (int kk = 0; kk < 2; ++kk) {
            int r = wn * 64 + n * 16 + lrow;
            bfrag[n * 2 + kk] = *(const bf16x8*)(Bsl + r * 64 + (((kk * 4 + lgrp) ^ (r & 7)) << 3));
          }
      }
      bf16x8 af0k0, af0k1, af1k0, af1k1;
      {
        int r0 = wm * 128 + (q * 2) * 16 + lrow;
        int r1 = wm * 128 + (q * 2 + 1) * 16 + lrow;
        af0k0 = *(const bf16x8*)(Asl + r0 * 64 + (((0 + lgrp) ^ (r0 & 7)) << 3));
        af0k1 = *(const bf16x8*)(Asl + r0 * 64 + (((4 + lgrp) ^ (r0 & 7)) << 3));
        af1k0 = *(const bf16x8*)(Asl + r1 * 64 + (((0 + lgrp) ^ (r1 & 7)) << 3));
        af1k1 = *(const bf16x8*)(Asl + r1 * 64 + (((4 + lgrp) ^ (r1 & 7)) << 3));
      }
      __builtin_amdgcn_s_setprio(1);
      #pragma unroll
      for (int n = 0; n < 4; ++n) {
        acc[q * 2 + 0][n] = mfma_bf16(af0k0, bfrag[n * 2 + 0], acc[q * 2 + 0][n]);
        acc[q * 2 + 1][n] = mfma_bf16(af1k0, bfrag[n * 2 + 0], acc[q * 2 + 1][n]);
      }
      #pragma unroll
      for (int n = 0; n < 4; ++n) {
        acc[q * 2 + 0][n] = mfma_bf16(af0k1, bfrag[n * 2 + 1], acc[q * 2 + 0][n]);
        acc[q * 2 + 1][n] = mfma_bf16(af1k1, bfrag[n * 2 + 1], acc[q * 2 + 1][n]);
      }
      __builtin_amdgcn_s_setprio(0);
      __builtin_amdgcn_s_barrier();                      // all reads done before next overwrite
    }
  }

  // epilogue: C frag layout col = lane&15, row = (lane>>4)*4 + j
  #pragma unroll
  for (int nf = 0; nf < 4; ++nf) {
    const int col = col0 + wn * 64 + nf * 16 + lrow;
    float bs = (EPI == 3) ? bias[col] : 0.0f;
    #pragma unroll
    for (int mf = 0; mf < 8; ++mf) {
      const int rbase = row0 + wm * 128 + mf * 16 + (lgrp << 2);
      #pragma unroll
      for (int j = 0; j < 4; ++j) {
        const int t = rbase + j;
        if (EPI == 1) {
          float val = acc[mf][nf][j] + bias[t];
          if (t < 768) val *= 0.125f;
          outB[(size_t)t * ldc + col] = (bf16)val;
        } else {
          if (t >= M) continue;
          float val = acc[mf][nf][j] + bs;
          outB[(size_t)t * 3072 + col] = (bf16)(0.5f * val * (1.0f + erff(val * 0.70710678118654752f)));
        }
      }
    }
  }
}

// ---------------- attention: one block per (b, head), 4 waves, 80 KiB LDS ----------------
__global__ __launch_bounds__(256) void attn_k(const bf16* __restrict__ Ct, bf16* __restrict__ O) {
  __shared__ alignas(16) bf16 smem[40960];
  bf16* Ks = smem;              // [208][64] xor-swizzled
  bf16* QP = smem + 13312;      // Qs [208][64] swizzled, later Ps [4][16][216]
  bf16* Vs = smem + 27136;      // [64][216], cols 200..215 zeroed
  const int bh = blockIdx.x;
  const int b = bh / 12, hh = bh - b * 12;
  const int tid = threadIdx.x, lane = tid & 63, wave = tid >> 6;
  const int lrow = lane & 15, lgrp = lane >> 4;
  const size_t tc0 = (size_t)b * 200;

  for (int task = tid; task < 1600; task += 256) {
    int d = task / 25, lc = task - d * 25;
    int l0 = lc * 8;
    const size_t cb = tc0 + l0;
    bf16x8 qv = *(const bf16x8*)(Ct + ((size_t)(d * 12 + hh)) * 6400 + cb);
    bf16x8 kv = *(const bf16x8*)(Ct + ((size_t)(768 + d * 12 + hh)) * 6400 + cb);
    bf16x8 vv = *(const bf16x8*)(Ct + ((size_t)(1536 + d * 12 + hh)) * 6400 + cb);
    #pragma unroll
    for (int e = 0; e < 8; ++e) {
      int l = l0 + e;
      int sw = ((((d >> 3) ^ (l & 7)) << 3) | (d & 7));
      Ks[l * 64 + sw] = kv[e];
      QP[l * 64 + sw] = qv[e];
    }
    *(bf16x8*)(Vs + d * 216 + l0) = vv;
  }
  for (int t2 = tid; t2 < 64 * 16; t2 += 256) {
    int d = t2 >> 4, c = 200 + (t2 & 15);
    Vs[d * 216 + c] = (bf16)0.0f;
  }
  __syncthreads();

  bf16x8 qa0[4], qa1[4];
  #pragma unroll
  for (int ii = 0; ii < 4; ++ii) {
    int rt = wave + ii * 4;
    if (rt < 13) {
      int r = rt * 16 + lrow;
      qa0[ii] = *(const bf16x8*)(QP + r * 64 + ((lgrp ^ (r & 7)) << 3));
      qa1[ii] = *(const bf16x8*)(QP + r * 64 + (((4 + lgrp) ^ (r & 7)) << 3));
    }
  }
  __syncthreads();

  bf16* Pw = QP + wave * (16 * 216);
  const bf16x8 zv = {};

  #pragma unroll
  for (int ii = 0; ii < 4; ++ii) {
    const int rt = wave + ii * 4;
    if (rt >= 13) break;
    f32x4 sacc[13];
    #pragma unroll
    for (int ct = 0; ct < 13; ++ct) {
      const int kr = ct * 16 + lrow;
      bf16x8 b0 = *(const bf16x8*)(Ks + kr * 64 + ((lgrp ^ (kr & 7)) << 3));
      bf16x8 b1 = *(const bf16x8*)(Ks + kr * 64 + (((4 + lgrp) ^ (kr & 7)) << 3));
      f32x4 s = {};
      s = mfma_bf16(qa0[ii], b0, s);
      s = mfma_bf16(qa1[ii], b1, s);
      sacc[ct] = s;
    }
    float inv4[4];
    #pragma unroll
    for (int j = 0; j < 4; ++j) {
      const int prow = (lgrp << 2) + j;
      float mx = -3.0e38f;
      #pragma unroll
      for (int ct = 0; ct < 13; ++ct) {
        int c = ct * 16 + lrow;
        if (c < 197) mx = fmaxf(mx, sacc[ct][j]);
      }
      #pragma unroll
      for (int o = 1; o < 16; o <<= 1) mx = fmaxf(mx, __shfl_xor(mx, o));
      float sum = 0.0f;
      #pragma unroll
      for (int ct = 0; ct < 13; ++ct) {
        int c = ct * 16 + lrow;
        float p = (c < 197) ? __expf(sacc[ct][j] - mx) : 0.0f;
        sum += p;
        Pw[prow * 216 + c] = (bf16)p;
      }
      #pragma unroll
      for (int o = 1; o < 16; o <<= 1) sum += __shfl_xor(sum, o);
      inv4[j] = 1.0f / sum;
    }
    f32x4 oacc[4] = {};
    #pragma unroll
    for (int mc = 0; mc < 7; ++mc) {
      bf16x8 pa;
      if (mc < 6) {
        pa = *(const bf16x8*)(Pw + lrow * 216 + mc * 32 + (lgrp << 3));
      } else {
        pa = *(const bf16x8*)(Pw + lrow * 216 + 192 + ((lgrp & 1) << 3));
        if (lgrp >= 2) pa = zv;
      }
      #pragma unroll
      for (int n2 = 0; n2 < 4; ++n2) {
        const int vr = n2 * 16 + lrow;
        bf16x8 vb;
        if (mc < 6) vb = *(const bf16x8*)(Vs + vr * 216 + mc * 32 + (lgrp << 3));
        else        vb = *(const bf16x8*)(Vs + vr * 216 + 192 + ((lgrp & 1) << 3));
        oacc[n2] = mfma_bf16(pa, vb, oacc[n2]);
      }
    }
    #pragma unroll
    for (int n2 = 0; n2 < 4; ++n2) {
      const int d = n2 * 16 + lrow;
      #pragma unroll
      for (int j = 0; j < 4; ++j) {
        const int qrow = rt * 16 + (lgrp << 2) + j;
        if (qrow < 197)
          O[((size_t)b * 197 + qrow) * 768 + hh * 64 + d] = (bf16)(oacc[n2][j] * inv4[j]);
      }
    }
  }
}

// ---------------- driver ----------------

extern "C" void kernel_launch(void* const* d_in, const int* in_sizes, int n_in,
                              void* d_out, int out_size, void* d_ws, size_t ws_size,
                              hipStream_t stream) {
  const float* x      = (const float*)d_in[0];
  const float* w_proj = (const float*)d_in[1];
  const float* b_proj = (const float*)d_in[2];
  const float* cls    = (const float*)d_in[3];
  const float* ln1g   = (const float*)d_in[4];
  const float* ln1b   = (const float*)d_in[5];
  const float* w_qkv  = (const float*)d_in[6];
  const float* b_qkv  = (const float*)d_in[7];
  const float* w_o    = (const float*)d_in[8];
  const float* b_o    = (const float*)d_in[9];
  const float* ln2g   = (const float*)d_in[10];
  const float* ln2b   = (const float*)d_in[11];
  const float* w_fc1  = (const float*)d_in[12];
  const float* b_fc1  = (const float*)d_in[13];
  const float* w_fc2  = (const float*)d_in[14];
  const float* b_fc2  = (const float*)d_in[15];
  const float* lnfg   = (const float*)d_in[16];
  const float* lnfb   = (const float*)d_in[17];
  const float* w_h    = (const float*)d_in[18];
  const float* b_h    = (const float*)d_in[19];
  const float* w_c    = (const float*)d_in[20];
  const float* b_c    = (const float*)d_in[21];
  float* out = (float*)d_out;

  uint8_t* ws = (uint8_t*)d_ws;
  size_t off = 0;
  auto alloc = [&](size_t bytes) -> void* {
    void* p = ws + off; off += (bytes + 255) & ~(size_t)255; return p;
  };
  float* h    = (float*)alloc(6400ull * 768 * 4);   // residual fp32 (t = b*197+l)
  bf16*  ybf  = (bf16*) alloc(6400ull * 768 * 2);   // LN out bf16 (plain OR b*200+l padded)
  bf16*  ct   = (bf16*) alloc(2304ull * 6400 * 2);  // QKV^T, cols b*200+l
  bf16*  ob   = (bf16*) alloc(6400ull * 768 * 2);   // attention out bf16
  bf16*  f1   = (bf16*) alloc(6400ull * 3072 * 2);  // FC1 out bf16
  float* pos  = (float*)alloc(197ull * 768 * 4);
  bf16* wprojB = (bf16*)alloc(768ull * 768 * 2);
  bf16* wqkvB  = (bf16*)alloc(2304ull * 768 * 2);
  bf16* woB    = (bf16*)alloc(768ull * 768 * 2);
  bf16* wfc1B  = (bf16*)alloc(3072ull * 768 * 2);
  bf16* wfc2B  = (bf16*)alloc(768ull * 3072 * 2);
  bf16* whB    = (bf16*)alloc(768ull * 768 * 2);
  bf16* wcB    = (bf16*)alloc(1024ull * 768 * 2);   // rows 1000..1023 poison (finite)
  bf16* repB   = (bf16*)alloc(128ull * 768 * 2);    // rows 32..127 poison
  bf16* hidB   = (bf16*)alloc(128ull * 768 * 2);
  bf16* patches = f1;   // alias: patches dead before FC1 first writes f1

  f2b_k<<<(768 * 768 + 255) / 256, 256, 0, stream>>>(w_proj, wprojB, 768 * 768);
  f2b_k<<<(2304 * 768 + 255) / 256, 256, 0, stream>>>(w_qkv, wqkvB, 2304 * 768);
  f2b_k<<<(768 * 768 + 255) / 256, 256, 0, stream>>>(w_o, woB, 768 * 768);
  f2b_k<<<(3072 * 768 + 255) / 256, 256, 0, stream>>>(w_fc1, wfc1B, 3072 * 768);
  f2b_k<<<(768 * 3072 + 255) / 256, 256, 0, stream>>>(w_fc2, wfc2B, 768 * 3072);
  f2b_k<<<(768 * 768 + 255) / 256, 256, 0, stream>>>(w_h, whB, 768 * 768);
  f2b_k<<<(1000 * 768 + 255) / 256, 256, 0, stream>>>(w_c, wcB, 1000 * 768);
  posenc_k<<<197, 256, 0, stream>>>(pos);
  patchify_k<<<6272 * 768 / 256, 256, 0, stream>>>(x, patches);
  gemm2<64, 0><<<dim3(49, 12), 256, 0, stream>>>(patches, wprojB, 6272, 768, 768, 768,
                                                 b_proj, pos, h, nullptr);
  cls_k<<<32, 256, 0, stream>>>(h, pos, cls);

  for (int layer = 0; layer < 12; ++layer) {
    ln4_k<1><<<1576, 256, 0, stream>>>(h, ln1g, ln1b, ybf, 6304, 768);
    // QKV^T: A = w_qkv [2304][768], B = ybf (padded rows, 6400) -> Ct [2304][6400]
    gemm8<1><<<dim3(9, 25), 512, 0, stream>>>(wqkvB, ybf, 2304, 6400, 768, 6400,
                                              b_qkv, ct);
    attn_k<<<384, 256, 0, stream>>>(ct, ob);
    gemm2<64, 2><<<dim3(50, 12), 256, 0, stream>>>(ob, woB, 6304, 768, 768, 768,
                                                   b_o, nullptr, h, nullptr);
    ln4_k<0><<<1576, 256, 0, stream>>>(h, ln2g, ln2b, ybf, 6304, 768);
    gemm8<3><<<dim3(25, 12), 512, 0, stream>>>(ybf, wfc1B, 6304, 3072, 768, 3072,
                                               b_fc1, f1);
    gemm2<64, 2><<<dim3(50, 12), 256, 0, stream>>>(f1, wfc2B, 6304, 768, 3072, 768,
                                                   b_fc2, nullptr, h, nullptr);
  }

  ln4_k<0><<<8, 256, 0, stream>>>(h, lnfg, lnfb, repB, 32, 197 * 768);
  gemm2<64, 4><<<dim3(1, 12), 256, 0, stream>>>(repB, whB, 32, 768, 768, 768,
                                                b_h, nullptr, nullptr, hidB);
  gemm2<64, 5><<<dim3(1, 16), 256, 0, stream>>>(hidB, wcB, 32, 1000, 768, 1000,
                                                b_c, nullptr, out, nullptr);
}

// Round 11
// 2777.233 us; speedup vs baseline: 1.1615x; 1.1615x over previous
//
#include <hip/hip_runtime.h>
#include <hip/hip_bf16.h>

// ViT forward, MI355X gfx950. Round 11: R9 base (best: 2761us) + LDS-coalesced bf16
// epilogue for QKV/FC1 (C staged through swizzled Cs[128][128] overlaying As+Bs ->
// b128 row stores; kills 2x write amplification). K-loop untouched (R4-R10 lesson:
// occupancy beats intra-block pipelining at K=768).

typedef __bf16 bf16;
typedef __bf16 bf16x8 __attribute__((ext_vector_type(8)));
typedef __bf16 bf16x4 __attribute__((ext_vector_type(4)));
typedef float  f32x4  __attribute__((ext_vector_type(4)));

typedef __attribute__((address_space(1))) const unsigned int gu32;
typedef __attribute__((address_space(3))) unsigned int lu32;

static __device__ __forceinline__ f32x4 mfma_bf16(bf16x8 a, bf16x8 b, f32x4 c) {
  return __builtin_amdgcn_mfma_f32_16x16x32_bf16(a, b, c, 0, 0, 0);
}
static __device__ __forceinline__ void gll16(const bf16* g, bf16* l) {
  __builtin_amdgcn_global_load_lds((gu32*)g, (lu32*)l, 16, 0, 0);
}

// ---------------- small setup kernels ----------------

__global__ __launch_bounds__(256) void f2b_k(const float* __restrict__ a, bf16* __restrict__ o, int n) {
  int i = blockIdx.x * 256 + threadIdx.x;
  if (i < n) o[i] = (bf16)a[i];
}

__global__ __launch_bounds__(256) void posenc_k(float* __restrict__ pos) {
  int l = blockIdx.x;
  for (int d = threadIdx.x; d < 768; d += 256) {
    int ieff = d & ~1;
    float ang = (float)l * expf(-(float)ieff * (9.210340371976184f / 768.0f)); // 10000^{-i/768}
    pos[l * 768 + d] = (d & 1) ? cosf(ang) : sinf(ang);
  }
}

// patches[t, c*256+i*16+j] = x[b, c, ph*16+i, pw*16+j],  t = b*196 + ph*14 + pw
__global__ __launch_bounds__(256) void patchify_k(const float* __restrict__ x, bf16* __restrict__ p) {
  int idx = blockIdx.x * 256 + threadIdx.x;     // 6272*768 exact
  int t = idx / 768, col = idx - t * 768;
  int b = t / 196, pp = t - b * 196;
  int ph = pp / 14, pw = pp - ph * 14;
  int c = col >> 8, r = col & 255, i = r >> 4, j = r & 15;
  p[idx] = (bf16)x[((b * 3 + c) * 224 + ph * 16 + i) * 224 + pw * 16 + j];
}

// CLS row: h[b*197+0, :] = cls + pos[0]
__global__ __launch_bounds__(256) void cls_k(float* __restrict__ h, const float* __restrict__ pos,
                                             const float* __restrict__ cls) {
  int b = blockIdx.x;
  for (int d = threadIdx.x; d < 768; d += 256)
    h[((size_t)b * 197) * 768 + d] = cls[d] + pos[d];
}

// LayerNorm over 768, one wave per row, 4 rows/block, bf16 out.
// PAD=1: output row index remapped t=b*197+l -> b*200+l (QKV-GEMM B operand layout).
template<int PAD>
__global__ __launch_bounds__(256) void ln4_k(const float* __restrict__ x, const float* __restrict__ g,
                                             const float* __restrict__ bb, bf16* __restrict__ y,
                                             int nrows, int instride) {
  const int wave = threadIdx.x >> 6, lane = threadIdx.x & 63;
  const int row = blockIdx.x * 4 + wave;
  if (row >= nrows) return;
  const float4* x4 = (const float4*)(x + (size_t)row * instride);
  float4 v0 = x4[lane], v1 = x4[lane + 64], v2 = x4[lane + 128];
  float s  = v0.x + v0.y + v0.z + v0.w + v1.x + v1.y + v1.z + v1.w + v2.x + v2.y + v2.z + v2.w;
  float s2 = v0.x*v0.x + v0.y*v0.y + v0.z*v0.z + v0.w*v0.w
           + v1.x*v1.x + v1.y*v1.y + v1.z*v1.z + v1.w*v1.w
           + v2.x*v2.x + v2.y*v2.y + v2.z*v2.z + v2.w*v2.w;
  #pragma unroll
  for (int o = 1; o < 64; o <<= 1) { s += __shfl_xor(s, o); s2 += __shfl_xor(s2, o); }
  float m = s * (1.0f / 768.0f);
  float inv = rsqrtf(s2 * (1.0f / 768.0f) - m * m + 1e-5f);
  int orow = row;
  if (PAD) { int bq = row / 197; orow = row + bq * 3; }
  bf16* yr = y + (size_t)orow * 768;
  const float4* g4 = (const float4*)g;
  const float4* b4 = (const float4*)bb;
  #pragma unroll
  for (int i = 0; i < 3; ++i) {
    int idx = lane + i * 64;
    float4 vv = (i == 0) ? v0 : (i == 1) ? v1 : v2;
    float4 gv = g4[idx], bv = b4[idx];
    bf16x4 o;
    o[0] = (bf16)((vv.x - m) * inv * gv.x + bv.x);
    o[1] = (bf16)((vv.y - m) * inv * gv.y + bv.y);
    o[2] = (bf16)((vv.z - m) * inv * gv.z + bv.z);
    o[3] = (bf16)((vv.w - m) * inv * gv.w + bv.w);
    *(bf16x4*)(yr + idx * 4) = o;
  }
}

// ---------------- NT GEMM, R3 structure (single-buffer, 2D grid) ----------------
// C[M,N] = A[M,K] * B[N,K]^T. 128xBN tile, BK=64, 4 waves (2x2).
// EPI: 0=PROJ (h row remap + pos add, fp32)  1=QKVT (bf16, bias by ROW, rows<768 *0.125)
//      2=ACCUM (outF[t*768+col]+=) 3=FC1 gelu (bf16, stride ldc)
//      4=TANH (bf16, stride 768)   5=GUARDED fp32 store (stride ldc, col<N)
// EPI 1/3: C staged via swizzled LDS Cs[128][128] (overlays As+Bs) -> b128 coalesced stores.
template<int BN, int EPI>
__global__ __launch_bounds__(256) void gemm2(
    const bf16* __restrict__ A, const bf16* __restrict__ B,
    int M, int N, int K, int ldc, const float* __restrict__ bias,
    const float* __restrict__ posw,
    float* __restrict__ outF, bf16* __restrict__ outB)
{
  constexpr int WN = (BN == 128) ? 64 : 32;
  constexpr int NI = WN / 16;
  constexpr int NB = BN / 32;
  __shared__ alignas(16) bf16 sm[128 * 64 + BN * 64];
  bf16* As = sm;
  bf16* Bs = sm + 128 * 64;
  const int tid = threadIdx.x;
  const int lane = tid & 63, wave = tid >> 6;
  const int wr = wave >> 1, wc = wave & 1;
  const int lrow = lane & 15, lgrp = lane >> 4;
  const int row0 = blockIdx.x * 128, col0 = blockIdx.y * BN;

  f32x4 acc[4][NI] = {};
  const bf16* Agb = A + (size_t)row0 * K;
  const bf16* Bgb = B + (size_t)col0 * K;
  const int srow = lane >> 3, schunk = lane & 7;
  const int nk = K >> 6;

  for (int kt = 0; kt < nk; ++kt) {
    const bf16* Ag = Agb + kt * 64;
    const bf16* Bg = Bgb + kt * 64;
    #pragma unroll
    for (int i = 0; i < 4; ++i) {
      int rr = (wave * 4 + i) * 8 + srow;
      int g = schunk ^ (rr & 7);
      gll16(Ag + (size_t)rr * K + g * 8, As + (wave * 4 + i) * 512);
    }
    #pragma unroll
    for (int i = 0; i < NB; ++i) {
      int rr = (wave * NB + i) * 8 + srow;
      int g = schunk ^ (rr & 7);
      gll16(Bg + (size_t)rr * K + g * 8, Bs + (wave * NB + i) * 512);
    }
    __syncthreads();
    #pragma unroll
    for (int kk = 0; kk < 2; ++kk) {
      bf16x8 af[4], bfr[NI];
      #pragma unroll
      for (int mi = 0; mi < 4; ++mi) {
        int r = wr * 64 + mi * 16 + lrow;
        af[mi] = *(const bf16x8*)(As + r * 64 + (((kk * 4 + lgrp) ^ (r & 7)) << 3));
      }
      #pragma unroll
      for (int ni = 0; ni < NI; ++ni) {
        int r = wc * WN + ni * 16 + lrow;
        bfr[ni] = *(const bf16x8*)(Bs + r * 64 + (((kk * 4 + lgrp) ^ (r & 7)) << 3));
      }
      #pragma unroll
      for (int mi = 0; mi < 4; ++mi)
        #pragma unroll
        for (int ni = 0; ni < NI; ++ni)
          acc[mi][ni] = mfma_bf16(af[mi], bfr[ni], acc[mi][ni]);
    }
    __syncthreads();
  }

  if constexpr (EPI == 1 || EPI == 3) {
    // stage C through swizzled LDS (overlays As+Bs; safe after final barrier)
    bf16* Cs = sm;   // [128][128], col swizz: idx = crow*128 + (ccol ^ ((crow&7)<<3))
    #pragma unroll
    for (int ni = 0; ni < NI; ++ni) {
      const int ccol = wc * WN + ni * 16 + lrow;
      const float cb = (EPI == 3) ? bias[col0 + ccol] : 0.0f;
      #pragma unroll
      for (int mi = 0; mi < 4; ++mi) {
        #pragma unroll
        for (int j = 0; j < 4; ++j) {
          const int crow = wr * 64 + mi * 16 + (lgrp << 2) + j;
          float val = acc[mi][ni][j];
          if constexpr (EPI == 1) {
            const int t = row0 + crow;
            val += bias[t];
            if (t < 768) val *= 0.125f;
          } else {
            val += cb;
            val = 0.5f * val * (1.0f + erff(val * 0.70710678118654752f));
          }
          Cs[crow * 128 + (ccol ^ ((crow & 7) << 3))] = (bf16)val;
        }
      }
    }
    __syncthreads();
    // coalesced store: thread -> (row r, 64-col half), 8 x b128
    const int r = tid >> 1, half = tid & 1;
    const int t = row0 + r;
    if (EPI == 1 || t < M) {
      bf16* dst = outB + (size_t)t * ldc + col0 + half * 64;
      const bf16* src = Cs + r * 128;
      #pragma unroll
      for (int k = 0; k < 8; ++k) {
        int c = (half * 64 + k * 8) ^ ((r & 7) << 3);
        *(bf16x8*)(dst + k * 8) = *(const bf16x8*)(src + c);
      }
    }
  } else {
    // epilogue: C frag layout col = lane&15, row = (lane>>4)*4 + j
    #pragma unroll
    for (int ni = 0; ni < NI; ++ni) {
      const int col = col0 + wc * WN + ni * 16 + lrow;
      float bs = (EPI == 5) ? ((col < N) ? bias[col] : 0.0f) : bias[col];
      #pragma unroll
      for (int mi = 0; mi < 4; ++mi) {
        const int rbase = row0 + wr * 64 + mi * 16 + (lgrp << 2);
        #pragma unroll
        for (int j = 0; j < 4; ++j) {
          const int t = rbase + j;
          if (t >= M) continue;
          float val = acc[mi][ni][j] + bs;
          if (EPI == 0) {
            int b = t / 196, p = t - b * 196;
            outF[((size_t)(b * 197 + 1 + p)) * 768 + col] = val + posw[(size_t)(1 + p) * 768 + col];
          } else if (EPI == 2) {
            outF[(size_t)t * 768 + col] += val;
          } else if (EPI == 4) {
            outB[(size_t)t * 768 + col] = (bf16)tanhf(val);
          } else {
            if (col < N) outF[(size_t)t * ldc + col] = val;
          }
        }
      }
    }
  }
}

// ---------------- attention: one block per (b, head), 4 waves, 80 KiB LDS ----------------
// Ct: QKV^T [2304][6400] bf16, cols = b*200 + l (rows n = comp*768 + d*12 + h; Q pre-scaled 1/8).
// O: [6304][768] bf16 (t = b*197 + l).
__global__ __launch_bounds__(256) void attn_k(const bf16* __restrict__ Ct, bf16* __restrict__ O) {
  __shared__ alignas(16) bf16 smem[40960];
  bf16* Ks = smem;              // [208][64] xor-swizzled
  bf16* QP = smem + 13312;      // Qs [208][64] swizzled, later Ps [4][16][216]
  bf16* Vs = smem + 27136;      // [64][216], cols 200..215 zeroed
  const int bh = blockIdx.x;
  const int b = bh / 12, hh = bh - b * 12;
  const int tid = threadIdx.x, lane = tid & 63, wave = tid >> 6;
  const int lrow = lane & 15, lgrp = lane >> 4;
  const size_t tc0 = (size_t)b * 200;

  for (int task = tid; task < 1600; task += 256) {
    int d = task / 25, lc = task - d * 25;
    int l0 = lc * 8;
    const size_t cb = tc0 + l0;
    bf16x8 qv = *(const bf16x8*)(Ct + ((size_t)(d * 12 + hh)) * 6400 + cb);
    bf16x8 kv = *(const bf16x8*)(Ct + ((size_t)(768 + d * 12 + hh)) * 6400 + cb);
    bf16x8 vv = *(const bf16x8*)(Ct + ((size_t)(1536 + d * 12 + hh)) * 6400 + cb);
    #pragma unroll
    for (int e = 0; e < 8; ++e) {
      int l = l0 + e;
      int sw = ((((d >> 3) ^ (l & 7)) << 3) | (d & 7));
      Ks[l * 64 + sw] = kv[e];
      QP[l * 64 + sw] = qv[e];
    }
    *(bf16x8*)(Vs + d * 216 + l0) = vv;
  }
  for (int t2 = tid; t2 < 64 * 16; t2 += 256) {
    int d = t2 >> 4, c = 200 + (t2 & 15);
    Vs[d * 216 + c] = (bf16)0.0f;
  }
  __syncthreads();

  bf16x8 qa0[4], qa1[4];
  #pragma unroll
  for (int ii = 0; ii < 4; ++ii) {
    int rt = wave + ii * 4;
    if (rt < 13) {
      int r = rt * 16 + lrow;
      qa0[ii] = *(const bf16x8*)(QP + r * 64 + ((lgrp ^ (r & 7)) << 3));
      qa1[ii] = *(const bf16x8*)(QP + r * 64 + (((4 + lgrp) ^ (r & 7)) << 3));
    }
  }
  __syncthreads();

  bf16* Pw = QP + wave * (16 * 216);
  const bf16x8 zv = {};

  #pragma unroll
  for (int ii = 0; ii < 4; ++ii) {
    const int rt = wave + ii * 4;
    if (rt >= 13) break;
    f32x4 sacc[13];
    #pragma unroll
    for (int ct = 0; ct < 13; ++ct) {
      const int kr = ct * 16 + lrow;
      bf16x8 b0 = *(const bf16x8*)(Ks + kr * 64 + ((lgrp ^ (kr & 7)) << 3));
      bf16x8 b1 = *(const bf16x8*)(Ks + kr * 64 + (((4 + lgrp) ^ (kr & 7)) << 3));
      f32x4 s = {};
      s = mfma_bf16(qa0[ii], b0, s);
      s = mfma_bf16(qa1[ii], b1, s);
      sacc[ct] = s;
    }
    float inv4[4];
    #pragma unroll
    for (int j = 0; j < 4; ++j) {
      const int prow = (lgrp << 2) + j;
      float mx = -3.0e38f;
      #pragma unroll
      for (int ct = 0; ct < 13; ++ct) {
        int c = ct * 16 + lrow;
        if (c < 197) mx = fmaxf(mx, sacc[ct][j]);
      }
      #pragma unroll
      for (int o = 1; o < 16; o <<= 1) mx = fmaxf(mx, __shfl_xor(mx, o));
      float sum = 0.0f;
      #pragma unroll
      for (int ct = 0; ct < 13; ++ct) {
        int c = ct * 16 + lrow;
        float p = (c < 197) ? __expf(sacc[ct][j] - mx) : 0.0f;
        sum += p;
        Pw[prow * 216 + c] = (bf16)p;
      }
      #pragma unroll
      for (int o = 1; o < 16; o <<= 1) sum += __shfl_xor(sum, o);
      inv4[j] = 1.0f / sum;
    }
    f32x4 oacc[4] = {};
    #pragma unroll
    for (int mc = 0; mc < 7; ++mc) {
      bf16x8 pa;
      if (mc < 6) {
        pa = *(const bf16x8*)(Pw + lrow * 216 + mc * 32 + (lgrp << 3));
      } else {
        pa = *(const bf16x8*)(Pw + lrow * 216 + 192 + ((lgrp & 1) << 3));
        if (lgrp >= 2) pa = zv;
      }
      #pragma unroll
      for (int n2 = 0; n2 < 4; ++n2) {
        const int vr = n2 * 16 + lrow;
        bf16x8 vb;
        if (mc < 6) vb = *(const bf16x8*)(Vs + vr * 216 + mc * 32 + (lgrp << 3));
        else        vb = *(const bf16x8*)(Vs + vr * 216 + 192 + ((lgrp & 1) << 3));
        oacc[n2] = mfma_bf16(pa, vb, oacc[n2]);
      }
    }
    #pragma unroll
    for (int n2 = 0; n2 < 4; ++n2) {
      const int d = n2 * 16 + lrow;
      #pragma unroll
      for (int j = 0; j < 4; ++j) {
        const int qrow = rt * 16 + (lgrp << 2) + j;
        if (qrow < 197)
          O[((size_t)b * 197 + qrow) * 768 + hh * 64 + d] = (bf16)(oacc[n2][j] * inv4[j]);
      }
    }
  }
}

// ---------------- driver ----------------

extern "C" void kernel_launch(void* const* d_in, const int* in_sizes, int n_in,
                              void* d_out, int out_size, void* d_ws, size_t ws_size,
                              hipStream_t stream) {
  const float* x      = (const float*)d_in[0];
  const float* w_proj = (const float*)d_in[1];
  const float* b_proj = (const float*)d_in[2];
  const float* cls    = (const float*)d_in[3];
  const float* ln1g   = (const float*)d_in[4];
  const float* ln1b   = (const float*)d_in[5];
  const float* w_qkv  = (const float*)d_in[6];
  const float* b_qkv  = (const float*)d_in[7];
  const float* w_o    = (const float*)d_in[8];
  const float* b_o    = (const float*)d_in[9];
  const float* ln2g   = (const float*)d_in[10];
  const float* ln2b   = (const float*)d_in[11];
  const float* w_fc1  = (const float*)d_in[12];
  const float* b_fc1  = (const float*)d_in[13];
  const float* w_fc2  = (const float*)d_in[14];
  const float* b_fc2  = (const float*)d_in[15];
  const float* lnfg   = (const float*)d_in[16];
  const float* lnfb   = (const float*)d_in[17];
  const float* w_h    = (const float*)d_in[18];
  const float* b_h    = (const float*)d_in[19];
  const float* w_c    = (const float*)d_in[20];
  const float* b_c    = (const float*)d_in[21];
  float* out = (float*)d_out;

  uint8_t* ws = (uint8_t*)d_ws;
  size_t off = 0;
  auto alloc = [&](size_t bytes) -> void* {
    void* p = ws + off; off += (bytes + 255) & ~(size_t)255; return p;
  };
  float* h    = (float*)alloc(6400ull * 768 * 4);   // residual fp32 (t = b*197+l)
  bf16*  ybf  = (bf16*) alloc(6400ull * 768 * 2);   // LN out bf16 (plain OR b*200+l padded)
  bf16*  ct   = (bf16*) alloc(2304ull * 6400 * 2);  // QKV^T, cols b*200+l
  bf16*  ob   = (bf16*) alloc(6400ull * 768 * 2);   // attention out bf16
  bf16*  f1   = (bf16*) alloc(6400ull * 3072 * 2);  // FC1 out bf16
  float* pos  = (float*)alloc(197ull * 768 * 4);
  bf16* wprojB = (bf16*)alloc(768ull * 768 * 2);
  bf16* wqkvB  = (bf16*)alloc(2304ull * 768 * 2);
  bf16* woB    = (bf16*)alloc(768ull * 768 * 2);
  bf16* wfc1B  = (bf16*)alloc(3072ull * 768 * 2);
  bf16* wfc2B  = (bf16*)alloc(768ull * 3072 * 2);
  bf16* whB    = (bf16*)alloc(768ull * 768 * 2);
  bf16* wcB    = (bf16*)alloc(1024ull * 768 * 2);   // rows 1000..1023 poison (finite)
  bf16* repB   = (bf16*)alloc(128ull * 768 * 2);    // rows 32..127 poison
  bf16* hidB   = (bf16*)alloc(128ull * 768 * 2);
  bf16* patches = f1;   // alias: patches dead before FC1 first writes f1

  f2b_k<<<(768 * 768 + 255) / 256, 256, 0, stream>>>(w_proj, wprojB, 768 * 768);
  f2b_k<<<(2304 * 768 + 255) / 256, 256, 0, stream>>>(w_qkv, wqkvB, 2304 * 768);
  f2b_k<<<(768 * 768 + 255) / 256, 256, 0, stream>>>(w_o, woB, 768 * 768);
  f2b_k<<<(3072 * 768 + 255) / 256, 256, 0, stream>>>(w_fc1, wfc1B, 3072 * 768);
  f2b_k<<<(768 * 3072 + 255) / 256, 256, 0, stream>>>(w_fc2, wfc2B, 768 * 3072);
  f2b_k<<<(768 * 768 + 255) / 256, 256, 0, stream>>>(w_h, whB, 768 * 768);
  f2b_k<<<(1000 * 768 + 255) / 256, 256, 0, stream>>>(w_c, wcB, 1000 * 768);
  posenc_k<<<197, 256, 0, stream>>>(pos);
  patchify_k<<<6272 * 768 / 256, 256, 0, stream>>>(x, patches);
  gemm2<64, 0><<<dim3(49, 12), 256, 0, stream>>>(patches, wprojB, 6272, 768, 768, 768,
                                                 b_proj, pos, h, nullptr);
  cls_k<<<32, 256, 0, stream>>>(h, pos, cls);

  for (int layer = 0; layer < 12; ++layer) {
    ln4_k<1><<<1576, 256, 0, stream>>>(h, ln1g, ln1b, ybf, 6304, 768);
    // QKV^T: A = w_qkv [2304][768], B = ybf (padded rows, 6400) -> Ct [2304][6400]
    gemm2<128, 1><<<dim3(18, 50), 256, 0, stream>>>(wqkvB, ybf, 2304, 6400, 768, 6400,
                                                    b_qkv, nullptr, nullptr, ct);
    attn_k<<<384, 256, 0, stream>>>(ct, ob);
    gemm2<64, 2><<<dim3(50, 12), 256, 0, stream>>>(ob, woB, 6304, 768, 768, 768,
                                                   b_o, nullptr, h, nullptr);
    ln4_k<0><<<1576, 256, 0, stream>>>(h, ln2g, ln2b, ybf, 6304, 768);
    gemm2<128, 3><<<dim3(50, 24), 256, 0, stream>>>(ybf, wfc1B, 6304, 3072, 768, 3072,
                                                    b_fc1, nullptr, nullptr, f1);
    gemm2<64, 2><<<dim3(50, 12), 256, 0, stream>>>(f1, wfc2B, 6304, 768, 3072, 768,
                                                   b_fc2, nullptr, h, nullptr);
  }

  ln4_k<0><<<8, 256, 0, stream>>>(h, lnfg, lnfb, repB, 32, 197 * 768);
  gemm2<64, 4><<<dim3(1, 12), 256, 0, stream>>>(repB, whB, 32, 768, 768, 768,
                                                b_h, nullptr, nullptr, hidB);
  gemm2<64, 5><<<dim3(1, 16), 256, 0, stream>>>(hidB, wcB, 32, 1000, 768, 1000,
                                                b_c, nullptr, out, nullptr);
}